// Round 2
// baseline (234.836 us; speedup 1.0000x reference)
//
#include <hip/hip_runtime.h>

#define S_TOKENS 16384
#define DMODEL   2048
#define NE       8
#define CAPACITY 2560

// ws layout (4-byte units):
//   [0, 16384)      int    expert idx per token
//   [16384, 32768)  float  gate per token
//   [32768, 37376)  float  partials[9][512]  (q-major: psum[0..7], zsum at q=8)

__global__ __launch_bounds__(512, 4) void logits_kernel(
    const float* __restrict__ x, const float* __restrict__ W,
    int* __restrict__ idx_out, float* __restrict__ gate_out,
    float* __restrict__ partials) {
    // WT split: WA[j] = {W[0][j],..,W[3][j]}, WB[j] = {W[4][j],..,W[7][j]} (64 KB)
    __shared__ float4 WA[DMODEL];
    __shared__ float4 WB[DMODEL];
    __shared__ float  sacc[16];    // [0..7] psum, [8] zsum

    const int tid  = threadIdx.x;
    const int wave = tid >> 6;
    const int lane = tid & 63;

    if (tid < 16) sacc[tid] = 0.0f;
    for (int j = tid; j < DMODEL; j += 512) {
        WA[j] = make_float4(W[j],          W[DMODEL + j],   W[2*DMODEL + j], W[3*DMODEL + j]);
        WB[j] = make_float4(W[4*DMODEL+j], W[5*DMODEL + j], W[6*DMODEL + j], W[7*DMODEL + j]);
    }
    __syncthreads();

    // 4 tokens per wave, one pass: block covers 32 tokens
    const int token0 = blockIdx.x * 32 + wave * 4;
    const float* __restrict__ x0 = x + (size_t)token0 * DMODEL;
    const float* __restrict__ x1 = x0 + DMODEL;
    const float* __restrict__ x2 = x1 + DMODEL;
    const float* __restrict__ x3 = x2 + DMODEL;

    float a0[NE], a1[NE], a2[NE], a3[NE];
    #pragma unroll
    for (int e = 0; e < NE; ++e) { a0[e]=0; a1[e]=0; a2[e]=0; a3[e]=0; }

    #pragma unroll 4
    for (int i = 0; i < DMODEL/64; ++i) {
        const int j = i*64 + lane;
        float xv0 = x0[j], xv1 = x1[j], xv2 = x2[j], xv3 = x3[j];
        float4 wa = WA[j];
        float4 wb = WB[j];
        float wv[NE] = {wa.x, wa.y, wa.z, wa.w, wb.x, wb.y, wb.z, wb.w};
        #pragma unroll
        for (int e = 0; e < NE; ++e) {
            float w = wv[e];
            a0[e] += xv0*w; a1[e] += xv1*w; a2[e] += xv2*w; a3[e] += xv3*w;
        }
    }

    // reduction with token-halving: lanes [q*16, q*16+16) end owning token q
    const bool hiHalf = (lane & 32) != 0;
    const bool oddQ   = (lane & 16) != 0;
    float lg[NE];
    #pragma unroll
    for (int e = 0; e < NE; ++e) {
        float s0 = a0[e] + __shfl_xor(a0[e], 32);
        float s1 = a1[e] + __shfl_xor(a1[e], 32);
        float s2 = a2[e] + __shfl_xor(a2[e], 32);
        float s3 = a3[e] + __shfl_xor(a3[e], 32);
        float u = hiHalf ? s2 : s0;   // even-numbered token of my half
        float v = hiHalf ? s3 : s1;   // odd-numbered token of my half
        u += __shfl_xor(u, 16);
        v += __shfl_xor(v, 16);
        float r = oddQ ? v : u;
        r += __shfl_xor(r, 8);
        r += __shfl_xor(r, 4);
        r += __shfl_xor(r, 2);
        r += __shfl_xor(r, 1);
        lg[e] = r;
    }

    // epilogue: each 16-lane quarter handles its own token (uniform within quarter)
    const int token = token0 + (lane >> 4);
    const int sub   = lane & 15;

    float m = lg[0]; int e = 0;
    #pragma unroll
    for (int k = 1; k < NE; ++k) { if (lg[k] > m) { m = lg[k]; e = k; } }
    float z = 0.0f;
    #pragma unroll
    for (int k = 0; k < NE; ++k) z += expf(lg[k] - m);
    float gate = 1.0f / z;                 // max prob = exp(m-m)/z
    float lz   = m + logf(z);

    if (sub == 0) {
        idx_out[token]  = e;
        gate_out[token] = gate;
        atomicAdd(&sacc[8], lz * lz);
    }
    if (sub < NE) {
        // binary select lg[sub]
        float b0 = (sub & 1) ? lg[1] : lg[0];
        float b1 = (sub & 1) ? lg[3] : lg[2];
        float b2 = (sub & 1) ? lg[5] : lg[4];
        float b3 = (sub & 1) ? lg[7] : lg[6];
        float c0 = (sub & 2) ? b1 : b0;
        float c1 = (sub & 2) ? b3 : b2;
        float ae = (sub & 4) ? c1 : c0;
        atomicAdd(&sacc[sub], expf(ae - m) * gate);
    }

    __syncthreads();
    if (tid < 9) partials[tid*512 + blockIdx.x] = sacc[tid];
}

__global__ __launch_bounds__(512, 1) void finalize_kernel(
    const int* __restrict__ idx, const float* __restrict__ gate,
    const float* __restrict__ partials, float* __restrict__ out) {
    __shared__ float facc[9];
    __shared__ int   cnt[256][9];   // [span][expert], stride 9 breaks bank alignment
    const int t    = threadIdx.x;
    const int wv   = t >> 6;
    const int lane = t & 63;

    if (t < 9) facc[t] = 0.0f;
    __syncthreads();

    // phase 0: reduce per-block partials (9 x 512)
    {
        float v = partials[0*512 + t];
        #pragma unroll
        for (int off = 32; off > 0; off >>= 1) v += __shfl_xor(v, off);
        if (lane == 0) atomicAdd(&facc[0], v);
    }
    #pragma unroll
    for (int q = 1; q < 9; ++q) {
        float v = partials[q*512 + t];
        #pragma unroll
        for (int off = 32; off > 0; off >>= 1) v += __shfl_xor(v, off);
        if (lane == 0) atomicAdd(&facc[q], v);
    }

    // phase 1: per-span (64 tokens) expert histogram via ballots; 8 waves x 32 spans
    const int spanBeg = wv * 32, spanEnd = spanBeg + 32;
    {
        int e = idx[spanBeg*64 + lane];
        for (int s = spanBeg; s < spanEnd; ++s) {
            int en = (s+1 < spanEnd) ? idx[(s+1)*64 + lane] : 0;
            #pragma unroll
            for (int q = 0; q < NE; ++q) {
                unsigned long long mk = __ballot(e == q);
                if (lane == q) cnt[s][q] = (int)__popcll(mk);
            }
            e = en;
        }
    }
    __syncthreads();

    // phase 2: Hillis-Steele inclusive scan over 256 spans (threads 0-255)
    int myc[NE];
    if (t < 256) {
        #pragma unroll
        for (int q = 0; q < NE; ++q) myc[q] = cnt[t][q];
    }
    for (int off = 1; off < 256; off <<= 1) {
        int v[NE];
        if (t < 256) {
            #pragma unroll
            for (int q = 0; q < NE; ++q) v[q] = (t >= off) ? cnt[t-off][q] : 0;
        }
        __syncthreads();
        if (t < 256) {
            #pragma unroll
            for (int q = 0; q < NE; ++q) cnt[t][q] += v[q];
        }
        __syncthreads();
    }

    // aux loss from inclusive totals (before exclusive rewrite)
    if (t == 0) {
        float lb = 0.0f;
        #pragma unroll
        for (int q = 0; q < NE; ++q) {
            float f = (float)cnt[255][q] * (1.0f/S_TOKENS);
            float p = facc[q] * (1.0f/S_TOKENS);
            lb += f * p;
        }
        out[2*S_TOKENS] = 0.01f * (facc[8] * (1.0f/S_TOKENS)) + 0.08f * lb;
    }
    __syncthreads();
    if (t < 256) {
        #pragma unroll
        for (int q = 0; q < NE; ++q) cnt[t][q] -= myc[q];   // now exclusive
    }
    __syncthreads();

    // phase 4: ranks + outputs
    {
        int   e = idx[spanBeg*64 + lane];
        float g = gate[spanBeg*64 + lane];
        for (int s = spanBeg; s < spanEnd; ++s) {
            int   en = (s+1 < spanEnd) ? idx[(s+1)*64 + lane]  : 0;
            float gn = (s+1 < spanEnd) ? gate[(s+1)*64 + lane] : 0.0f;
            unsigned long long mym = 0;
            #pragma unroll
            for (int q = 0; q < NE; ++q) {
                unsigned long long mk = __ballot(e == q);
                if (e == q) mym = mk;
            }
            unsigned long long lt = (1ull << lane) - 1ull;
            int rank = cnt[s][e] + (int)__popcll(mym & lt);
            int token = s*64 + lane;
            out[token] = (float)e;
            out[S_TOKENS + token] = (rank < CAPACITY) ? g : 0.0f;
            e = en; g = gn;
        }
    }
}

extern "C" void kernel_launch(void* const* d_in, const int* in_sizes, int n_in,
                              void* d_out, int out_size, void* d_ws, size_t ws_size,
                              hipStream_t stream) {
    const float* x = (const float*)d_in[0];
    const float* W = (const float*)d_in[1];
    float* out = (float*)d_out;

    int*   ws_idx  = (int*)d_ws;
    float* ws_gate = (float*)d_ws + 16384;
    float* ws_part = (float*)d_ws + 32768;   // 9*512 floats

    logits_kernel<<<512, 512, 0, stream>>>(x, W, ws_idx, ws_gate, ws_part);
    finalize_kernel<<<1, 512, 0, stream>>>(ws_idx, ws_gate, ws_part, out);
}